// Round 11
// baseline (571.198 us; speedup 1.0000x reference)
//
#include <hip/hip_runtime.h>
#include <hip/hip_bf16.h>

#define N_NODES 50000
#define N_EDGES 1600000
#define HEADS 8
#define NBK 196   // buckets: dst>>8
#define NBLK 196  // edge tiles: 196*8192 >= 1.6M
#define EPB 8192  // edges per bucket-build block

typedef unsigned short u16;
typedef unsigned char u8;
typedef unsigned int u32;
typedef __attribute__((ext_vector_type(8))) short bf16x8;
typedef __attribute__((ext_vector_type(4))) float f32x4;

__device__ __forceinline__ float bf2f(u16 u) {
  union { u32 i; float f; } v; v.i = ((u32)u) << 16; return v.f;
}
__device__ __forceinline__ float bflo(u32 p) {
  union { u32 i; float f; } v; v.i = p << 16; return v.f;
}
__device__ __forceinline__ float bfhi(u32 p) {
  union { u32 i; float f; } v; v.i = p & 0xffff0000u; return v.f;
}
__device__ __forceinline__ u16 f2bf(float f) {
  union { float f; u32 i; } v; v.f = f;
  u32 r = v.i + 0x7fff + ((v.i >> 16) & 1);  // RNE
  return (u16)(r >> 16);
}
__device__ __forceinline__ u32 pack2(float a, float b) {
  return (u32)f2bf(a) | ((u32)f2bf(b) << 16);
}
__device__ __forceinline__ int rfl(int x) { return __builtin_amdgcn_readfirstlane(x); }

// ---------------- dtype auto-detection ----------------
__global__ void k_detect(const u16* __restrict__ x, const u32* __restrict__ ei,
                         int* __restrict__ flags) {
  __shared__ int cbig, cnz;
  if (threadIdx.x == 0) { cbig = 0; cnz = 0; }
  __syncthreads();
  int lb = 0, ln = 0;
  for (int i = threadIdx.x; i < 4096; i += 256) {
    int ex = (x[i] >> 7) & 0xff;
    lb += (ex >= 140);
    if (i < 2048) ln += (ei[2 * i + 1] != 0);
  }
  atomicAdd(&cbig, lb); atomicAdd(&cnz, ln);
  __syncthreads();
  if (threadIdx.x == 0) {
    flags[0] = (cbig > 16) ? 1 : 0;   // 1: floats are fp32
    flags[1] = (cnz == 0) ? 1 : 0;    // 1: edge_index is int64
  }
}

// ---------------- converter: vectors -> fp32, W1/W2 -> transposed bf16 -------
__global__ void k_convsmall(const void* a1s, const void* a1d, const void* b1,
                            const void* gam, const void* bet, const void* a2s,
                            const void* a2d, const void* b2, const void* W1,
                            const void* W2, float* __restrict__ smallf,
                            u16* __restrict__ w1t, u16* __restrict__ w2t,
                            const int* __restrict__ flags) {
  int i = blockIdx.x * 256 + threadIdx.x;
  if (i >= 25408) return;
  bool f32 = flags[0] != 0;
  auto ld = [&](const void* p, int off) -> float {
    return f32 ? ((const float*)p)[off] : bf2f(((const u16*)p)[off]);
  };
  if (i >= 17216) {            // W2T[n][k], n<64, k<128  <- W2[k*64+n]
    int j = i - 17216, n = j >> 7, k = j & 127;
    w2t[j] = f2bf(ld(W2, k * 64 + n));
  } else if (i >= 832) {       // W1T[n][k], n<128, k<128 <- W1[k*128+n]
    int j = i - 832, n = j >> 7, k = j & 127;
    w1t[j] = f2bf(ld(W1, k * 128 + n));
  } else {
    const void* src; int off;
    if (i >= 768)      { src = b2;  off = i - 768; }
    else if (i >= 704) { src = a2d; off = i - 704; }
    else if (i >= 640) { src = a2s; off = i - 640; }
    else if (i >= 512) { src = bet; off = i - 512; }
    else if (i >= 384) { src = gam; off = i - 384; }
    else if (i >= 256) { src = b1;  off = i - 256; }
    else if (i >= 128) { src = a1d; off = i - 128; }
    else               { src = a1s; off = i; }
    smallf[i] = ld(src, off);
  }
}

// ---------------- CSR build (atomic-free two-level counting sort) ----------
// Phase 1: histogram + per-edge rank (rank within (bucket, tile), < 8192)
__global__ __launch_bounds__(256) void k_hist(const int* __restrict__ ei,
                                              int* __restrict__ H,
                                              int* __restrict__ totals,
                                              u16* __restrict__ rank16,
                                              const int* __restrict__ flags) {
  __shared__ int hist[NBK];
  int t = threadIdx.x, blk = blockIdx.x;
  for (int i = t; i < NBK; i += 256) hist[i] = 0;
  __syncthreads();
  bool i64 = flags[1] != 0;
  int base = blk * EPB;
  for (int k = 0; k < 32; k++) {
    int e = base + k * 256 + t;
    if (e < N_EDGES) {
      int d = i64 ? ei[2 * (N_EDGES + e)] : ei[N_EDGES + e];
      rank16[e] = (u16)atomicAdd(&hist[d >> 8], 1);
    }
  }
  __syncthreads();
  for (int i = t; i < NBK; i += 256) {
    H[i * NBLK + blk] = hist[i];
    atomicAdd(&totals[i], hist[i]);
  }
}

// per-bucket scan over blocks; bucket bases computed inline from totals
__global__ void k_scan_blk(const int* __restrict__ H, const int* __restrict__ totals,
                           int* __restrict__ P) {
  __shared__ int tb[256], tmp[256];
  int t = threadIdx.x, b = blockIdx.x;
  int v0 = (t < NBK) ? totals[t] : 0;
  tb[t] = v0; __syncthreads();
  for (int o = 1; o < 256; o <<= 1) {
    int x = (t >= o) ? tb[t - o] : 0; __syncthreads();
    tb[t] += x; __syncthreads();
  }
  int base = (b == 0) ? 0 : tb[b - 1];
  int v = (t < NBLK) ? H[b * NBLK + t] : 0;
  tmp[t] = v; __syncthreads();
  for (int o = 1; o < 256; o <<= 1) {
    int x = (t >= o) ? tmp[t - o] : 0; __syncthreads();
    tmp[t] += x; __syncthreads();
  }
  if (t < NBLK) P[b * NBLK + t] = base + tmp[t] - v;
}

// Bucket scatter: counts come from H, ranks from rank16 (no atomic pass).
__global__ __launch_bounds__(256) void k_bucket(const int* __restrict__ ei,
                                                const int* __restrict__ H,
                                                const int* __restrict__ P,
                                                const u16* __restrict__ rank16,
                                                u32* __restrict__ buf,
                                                const int* __restrict__ flags) {
  __shared__ u32 sv[EPB];
  __shared__ u8  sk8[EPB];
  __shared__ int scn[NBK], Pl[NBK], tmp[256];
  int t = threadIdx.x, blk = blockIdx.x;
  int base = blk * EPB;
  int nE = N_EDGES - base; if (nE > EPB) nE = EPB;
  // counts + P column from global
  int v = (t < NBK) ? H[t * NBLK + blk] : 0;
  if (t < NBK) Pl[t] = P[t * NBLK + blk];
  tmp[t] = v; __syncthreads();
  for (int o = 1; o < 256; o <<= 1) {
    int x = (t >= o) ? tmp[t - o] : 0; __syncthreads();
    tmp[t] += x; __syncthreads();
  }
  if (t < NBK) scn[t] = tmp[t] - v;
  __syncthreads();
  bool i64 = flags[1] != 0;
  for (int k = 0; k < EPB / 256; k++) {
    int li = k * 256 + t, e = base + li;
    if (li < nE) {
      int s = i64 ? ei[2 * e] : ei[e];
      int d = i64 ? ei[2 * (N_EDGES + e)] : ei[N_EDGES + e];
      int key = d >> 8;
      int pos = scn[key] + (int)rank16[e];
      sv[pos] = ((u32)(d & 255) << 16) | (u32)s;
      sk8[pos] = (u8)key;
    }
  }
  __syncthreads();
  for (int i = t; i < nE; i += 256) {
    int b = sk8[i];
    buf[Pl[b] + (i - scn[b])] = sv[i];
  }
}

__global__ __launch_bounds__(256) void k_csr(const u32* __restrict__ buf,
                                             const int* __restrict__ totals,
                                             int* __restrict__ row_start,
                                             int* __restrict__ deg,
                                             int* __restrict__ csr, int N) {
  __shared__ int tb[256], cnt[256], scn[256], cur[256];
  int b = blockIdx.x, t = threadIdx.x;
  int v0 = (t < NBK) ? totals[t] : 0;
  tb[t] = v0; __syncthreads();
  for (int o = 1; o < 256; o <<= 1) {
    int x = (t >= o) ? tb[t - o] : 0; __syncthreads();
    tb[t] += x; __syncthreads();
  }
  int lo = (b == 0) ? 0 : tb[b - 1];
  int hi = tb[b];
  cnt[t] = 0; __syncthreads();
  for (int e = lo + t; e < hi; e += 256) atomicAdd(&cnt[(buf[e] >> 16) & 255], 1);
  __syncthreads();
  int v = cnt[t];
  scn[t] = v; __syncthreads();
  for (int o = 1; o < 256; o <<= 1) {
    int x = (t >= o) ? scn[t - o] : 0; __syncthreads();
    scn[t] += x; __syncthreads();
  }
  int excl = scn[t] - v;
  int node = b * 256 + t;
  if (node < N) { row_start[node] = lo + excl; deg[node] = v; }
  cur[t] = lo + excl;
  __syncthreads();
  for (int e = lo + t; e < hi; e += 256) {
    u32 p = buf[e];
    int pos = atomicAdd(&cur[(p >> 16) & 255], 1);
    csr[pos] = p & 0xffff;
  }
}

// ---------------- MFMA GEMM: A[M,128] x BT[NCOLS,128] -> bf16 C row-major ---
template <int NCOLS, bool EPI, bool ALPHA1, bool AFLAG>
__global__ __launch_bounds__(256) void k_gemm_mfma(const void* __restrict__ A,
                                                   const u16* __restrict__ BT,
                                                   const float* __restrict__ bnsum,
                                                   const float* __restrict__ bnsq,
                                                   const float* __restrict__ gamma,
                                                   const float* __restrict__ beta,
                                                   const float* __restrict__ va,
                                                   const float* __restrict__ vb,
                                                   float* __restrict__ as_out,
                                                   float* __restrict__ ad_out,
                                                   u16* __restrict__ C, int M,
                                                   const int* __restrict__ flags) {
  constexpr int KP = 136;
  constexpr int NT = NCOLS / 16;
  __shared__ u16 As[64 * KP];
  __shared__ u16 Bs[NCOLS * KP];
  __shared__ float sSc[128], sSh[128];
  int t = threadIdx.x;
  int row0 = blockIdx.x * 64;
  bool af32 = AFLAG ? (flags[0] != 0) : false;

  if (EPI) {
    if (t < 128) {
      float mu = bnsum[t] * (1.f / (float)N_NODES);
      float var = fmaxf(bnsq[t] * (1.f / (float)N_NODES) - mu * mu, 0.f);
      float sc = gamma[t] * rsqrtf(var + 1e-5f);
      sSc[t] = sc; sSh[t] = beta[t] - mu * sc;
    }
    __syncthreads();
  }

  for (int i = t; i < NCOLS * 16; i += 256) {
    int n = i >> 4, q = i & 15;
    *(uint4*)&Bs[n * KP + q * 8] = ((const uint4*)BT)[n * 16 + q];
  }
  for (int i = t; i < 64 * 32; i += 256) {
    int r = i >> 5, c4 = i & 31;
    int row = row0 + r;
    uint2 pk = make_uint2(0u, 0u);
    if (row < M) {
      if (EPI) {
        uint2 p = ((const uint2*)A)[(size_t)row * 32 + c4];
        int c = c4 * 4;
        float v0 = bflo(p.x), v1 = bfhi(p.x), v2 = bflo(p.y), v3 = bfhi(p.y);
        v0 = fmaf(v0, sSc[c],     sSh[c]);     v0 = v0 > 0.f ? v0 : __expf(v0) - 1.f;
        v1 = fmaf(v1, sSc[c + 1], sSh[c + 1]); v1 = v1 > 0.f ? v1 : __expf(v1) - 1.f;
        v2 = fmaf(v2, sSc[c + 2], sSh[c + 2]); v2 = v2 > 0.f ? v2 : __expf(v2) - 1.f;
        v3 = fmaf(v3, sSc[c + 3], sSh[c + 3]); v3 = v3 > 0.f ? v3 : __expf(v3) - 1.f;
        pk.x = pack2(v0, v1); pk.y = pack2(v2, v3);
      } else if (af32) {
        float4 v = ((const float4*)A)[(size_t)row * 32 + c4];
        pk.x = pack2(v.x, v.y); pk.y = pack2(v.z, v.w);
      } else {
        pk = ((const uint2*)A)[(size_t)row * 32 + c4];
      }
    }
    *(uint2*)&As[r * KP + c4 * 4] = pk;
  }
  __syncthreads();

  int lane = t & 63, w = t >> 6;
  int m = lane & 15, quad = lane >> 4;
  f32x4 acc[NT];
#pragma unroll
  for (int nt = 0; nt < NT; nt++) acc[nt] = (f32x4)(0.f);
  const u16* aBase = &As[(w * 16 + m) * KP + quad * 8];
  const u16* bBase = &Bs[m * KP + quad * 8];
#pragma unroll
  for (int ks = 0; ks < 4; ks++) {
    bf16x8 af = *(const bf16x8*)(aBase + ks * 32);
#pragma unroll
    for (int nt = 0; nt < NT; nt++) {
      bf16x8 bf = *(const bf16x8*)(bBase + nt * 16 * KP + ks * 32);
      acc[nt] = __builtin_amdgcn_mfma_f32_16x16x32_bf16(af, bf, acc[nt], 0, 0, 0);
    }
  }
  int orow0 = row0 + w * 16 + quad * 4;
#pragma unroll
  for (int nt = 0; nt < NT; nt++) {
#pragma unroll
    for (int r = 0; r < 4; r++) {
      int row = orow0 + r;
      if (row < M) C[(size_t)row * NCOLS + nt * 16 + m] = f2bf(acc[nt][r]);
    }
  }
  if (ALPHA1) {
    float pav[NT], pbv[NT];
#pragma unroll
    for (int nt = 0; nt < NT; nt++) { pav[nt] = va[nt * 16 + m]; pbv[nt] = vb[nt * 16 + m]; }
#pragma unroll
    for (int r = 0; r < 4; r++) {
      int row = orow0 + r;
#pragma unroll
      for (int nt = 0; nt < NT; nt++) {
        float vs = acc[nt][r] * pav[nt];
        float vd = acc[nt][r] * pbv[nt];
        vs += __shfl_xor(vs, 1); vd += __shfl_xor(vd, 1);
        vs += __shfl_xor(vs, 2); vd += __shfl_xor(vd, 2);
        vs += __shfl_xor(vs, 4); vd += __shfl_xor(vd, 4);
        vs += __shfl_xor(vs, 8); vd += __shfl_xor(vd, 8);
        if (row < M && m == 0) { as_out[row * 8 + nt] = vs; ad_out[row * 8 + nt] = vd; }
      }
    }
  }
  if (EPI) {
    float pav[NT], pbv[NT];
#pragma unroll
    for (int nt = 0; nt < NT; nt++) { pav[nt] = va[nt * 16 + m]; pbv[nt] = vb[nt * 16 + m]; }
#pragma unroll
    for (int r = 0; r < 4; r++) {
      float vs = 0.f, vd = 0.f;
#pragma unroll
      for (int nt = 0; nt < NT; nt++) {
        vs = fmaf(acc[nt][r], pav[nt], vs);
        vd = fmaf(acc[nt][r], pbv[nt], vd);
      }
      vs += __shfl_xor(vs, 1); vd += __shfl_xor(vd, 1);
      vs += __shfl_xor(vs, 2); vd += __shfl_xor(vd, 2);
      vs += __shfl_xor(vs, 4); vd += __shfl_xor(vd, 4);
      vs += __shfl_xor(vs, 8); vd += __shfl_xor(vd, 8);
      int row = orow0 + r;
      if (row < M && m == 0) { as_out[row] = vs; ad_out[row] = vd; }
    }
  }
}

// ---------------- aggregation layer 1 (half-node range) + fused BN stats ----
// Round-6/10 proven loop; BN accumulated in registers, reduced once per block.
__global__ __launch_bounds__(256) void k_agg1(const u16* __restrict__ h1b,
                                              const float* __restrict__ as_,
                                              const float* __restrict__ ad_,
                                              const int* __restrict__ csr,
                                              const int* __restrict__ row_start,
                                              const int* __restrict__ deg,
                                              const float* __restrict__ b1,
                                              u16* __restrict__ out,
                                              float* __restrict__ gsum,
                                              float* __restrict__ gsq,
                                              int nodeBase, int N) {
  __shared__ float lsum[128], lsq[128];
  int t = threadIdx.x;
  if (t < 128) { lsum[t] = 0.f; lsq[t] = 0.f; }
  __syncthreads();
  int node = nodeBase + blockIdx.x * 4 + (t >> 6);
  int l = t & 63;
  if (node < N) {
    int head = l >> 3, sub = l & 7;
    int gbase = l & 56;
    int node_u = rfl(node);
    int st = rfl(row_start[node_u]);
    int cnt = rfl(deg[node_u]);
    const int* cp = csr + st;
    const u32* h32 = (const u32*)h1b;
    float ad = ad_[(node_u << 3) | head];
    float sp = 0.f, a0 = 0.f, a1 = 0.f;
    int j = 0;
    for (; j + 8 <= cnt; j += 8) {
      int ssub = cp[j + sub];
      float e = as_[(ssub << 3) | head] + ad;
      e = fmaxf(e, 0.2f * e);
      float p = __expf(e);
      sp += p;
#pragma unroll
      for (int k = 0; k < 8; k++) {
        int sk = cp[j + k];                       // uniform -> s_load
        float pk = __shfl(p, gbase | k);
        u32 hv = h32[(sk << 6) | l];
        a0 = fmaf(pk, bflo(hv), a0);
        a1 = fmaf(pk, bfhi(hv), a1);
      }
    }
    for (; j < cnt; j++) {
      int s0 = cp[j];
      float e0 = as_[(s0 << 3) | head] + ad;
      e0 = fmaxf(e0, 0.2f * e0);
      float p0 = __expf(e0);
      if (sub == 0) sp += p0;
      u32 hv = h32[(s0 << 6) | l];
      a0 = fmaf(p0, bflo(hv), a0); a1 = fmaf(p0, bfhi(hv), a1);
    }
    { // self-loop
      float e0 = as_[(node_u << 3) | head] + ad;
      e0 = fmaxf(e0, 0.2f * e0);
      float p0 = __expf(e0);
      if (sub == 0) sp += p0;
      u32 hv = h32[((size_t)node_u << 6) | l];
      a0 = fmaf(p0, bflo(hv), a0); a1 = fmaf(p0, bfhi(hv), a1);
    }
    sp += __shfl_xor(sp, 1);
    sp += __shfl_xor(sp, 2);
    sp += __shfl_xor(sp, 4);
    float inv = 1.f / (sp + 1e-16f);
    int c0 = l * 2;
    float r0 = fmaf(a0, inv, b1[c0]);
    float r1 = fmaf(a1, inv, b1[c0 + 1]);
    ((u32*)out)[((size_t)node_u << 6) + l] = pack2(r0, r1);
    // BN stats: lane owns channels c0, c0+1; block-end LDS reduce (not in loop)
    atomicAdd(&lsum[c0], r0);     atomicAdd(&lsq[c0], r0 * r0);
    atomicAdd(&lsum[c0 + 1], r1); atomicAdd(&lsq[c0 + 1], r1 * r1);
  }
  __syncthreads();
  if (t < 128) {
    atomicAdd(&gsum[t], lsum[t]);
    atomicAdd(&gsq[t], lsq[t]);
  }
}

// ---------------- aggregation layer 2 -> output (round-6/10 proven) ---------
__global__ __launch_bounds__(256) void k_agg2(const u16* __restrict__ h2b,
                                              const float* __restrict__ as_,
                                              const float* __restrict__ ad_,
                                              const int* __restrict__ csr,
                                              const int* __restrict__ row_start,
                                              const int* __restrict__ deg,
                                              const float* __restrict__ b2,
                                              void* __restrict__ out,
                                              const int* __restrict__ flags, int N) {
  int node = blockIdx.x * 4 + (threadIdx.x >> 6);
  if (node >= N) return;
  int l = threadIdx.x & 63;
  int sub = l & 7, gbase = l & 56;
  int node_u = rfl(node);
  int st = rfl(row_start[node_u]);
  int cnt = rfl(deg[node_u]);
  const int* cp = csr + st;
  float ad = ad_[node_u];
  float sp = 0.f, a = 0.f;
  int j = 0;
  for (; j + 8 <= cnt; j += 8) {
    int ssub = cp[j + sub];
    float e = as_[ssub] + ad;
    e = fmaxf(e, 0.2f * e);
    float p = __expf(e);
    sp += p;
#pragma unroll
    for (int k = 0; k < 8; k++) {
      int sk = cp[j + k];                         // uniform -> s_load
      float pk = __shfl(p, gbase | k);
      a = fmaf(pk, bf2f((h2b + (sk << 6))[l]), a);
    }
  }
  for (; j < cnt; j++) {
    int s0 = cp[j];
    float e0 = as_[s0] + ad;
    e0 = fmaxf(e0, 0.2f * e0);
    float p0 = __expf(e0);
    if (sub == 0) sp += p0;
    a = fmaf(p0, bf2f((h2b + (s0 << 6))[l]), a);
  }
  { // self-loop
    float e0 = as_[node_u] + ad;
    e0 = fmaxf(e0, 0.2f * e0);
    float p0 = __expf(e0);
    if (sub == 0) sp += p0;
    a = fmaf(p0, bf2f((h2b + (node_u << 6))[l]), a);
  }
  sp += __shfl_xor(sp, 1);
  sp += __shfl_xor(sp, 2);
  sp += __shfl_xor(sp, 4);
  float r = a / (sp + 1e-16f) + b2[l];
  size_t idx = ((size_t)node_u << 6) + l;
  if (flags[0]) ((float*)out)[idx] = r;
  else          ((u16*)out)[idx] = f2bf(r);
}

extern "C" void kernel_launch(void* const* d_in, const int* in_sizes, int n_in,
                              void* d_out, int out_size, void* d_ws, size_t ws_size,
                              hipStream_t stream) {
  const void* x   = d_in[0];
  const int*  ei  = (const int*)d_in[1];
  const void* W1  = d_in[2];
  const void* a1s = d_in[3];
  const void* a1d = d_in[4];
  const void* b1  = d_in[5];
  const void* gam = d_in[6];
  const void* bet = d_in[7];
  const void* W2  = d_in[8];
  const void* a2s = d_in[9];
  const void* a2d = d_in[10];
  const void* b2  = d_in[11];

  char* ws = (char*)d_ws;
  size_t off = 0;
  auto alloc = [&](size_t bytes) -> void* {
    void* p = ws + off;
    off += (bytes + 255) & ~(size_t)255;
    return p;
  };
  int* flags = (int*)alloc(256);
  // zero region: totals[196] pad 1024 | gsum[128] | gsq[128]
  char* zreg = (char*)alloc(2048);
  int* totals = (int*)zreg;
  float* gsum = (float*)(zreg + 1024);
  float* gsq  = gsum + 128;
  int* H  = (int*)alloc((size_t)NBK * NBLK * 4);
  int* P  = (int*)alloc((size_t)NBK * NBLK * 4);
  u16* rank16 = (u16*)alloc((size_t)N_EDGES * 2);
  u32* ebuf = (u32*)alloc((size_t)N_EDGES * 4);
  int* csr = (int*)alloc((size_t)N_EDGES * 4);
  int* row_start = (int*)alloc((size_t)N_NODES * 4);
  int* deg = (int*)alloc((size_t)N_NODES * 4);
  float* smallf = (float*)alloc(832 * 4);
  float* a1sf = smallf;        float* a1df = smallf + 128;
  float* b1f  = smallf + 256;  float* gamf = smallf + 384;
  float* betf = smallf + 512;  float* a2sf = smallf + 640;
  float* a2df = smallf + 704;  float* b2f  = smallf + 768;
  u16* w1t = (u16*)alloc(16384 * 2);
  u16* w2t = (u16*)alloc(8192 * 2);
  u16* h1b  = (u16*)alloc((size_t)N_NODES * 128 * 2);
  u16* h1ob = (u16*)alloc((size_t)N_NODES * 128 * 2);
  u16* h2b  = (u16*)alloc((size_t)N_NODES * 64 * 2);
  float* al1s = (float*)alloc((size_t)N_NODES * 8 * 4);
  float* al1d = (float*)alloc((size_t)N_NODES * 8 * 4);
  float* al2s = (float*)alloc((size_t)N_NODES * 4);
  float* al2d = (float*)alloc((size_t)N_NODES * 4);
  if (off > ws_size) return;

  hipMemsetAsync(zreg, 0, 2048, stream);
  k_detect<<<1, 256, 0, stream>>>((const u16*)x, (const u32*)ei, flags);
  k_convsmall<<<100, 256, 0, stream>>>(a1s, a1d, b1, gam, bet, a2s, a2d, b2, W1, W2,
                                       smallf, w1t, w2t, flags);

  // ---- CSR build ----
  k_hist<<<NBLK, 256, 0, stream>>>(ei, H, totals, rank16, flags);
  k_scan_blk<<<NBK, 256, 0, stream>>>(H, totals, P);
  k_bucket<<<NBLK, 256, 0, stream>>>(ei, H, P, rank16, ebuf, flags);
  k_csr<<<NBK, 256, 0, stream>>>(ebuf, totals, row_start, deg, csr, N_NODES);

  // ---- layer 1 (alpha1 fused into GEMM epilogue; BN stats fused into agg1) --
  k_gemm_mfma<128, false, true, true><<<(N_NODES + 63) / 64, 256, 0, stream>>>(
      x, w1t, nullptr, nullptr, nullptr, nullptr, a1sf, a1df, al1s, al1d,
      h1b, N_NODES, flags);
  // split into two half-node dispatches (diagnostic: surfaces kernel #2 in top-5)
  k_agg1<<<6250, 256, 0, stream>>>(h1b, al1s, al1d, csr, row_start, deg,
                                   b1f, h1ob, gsum, gsq, 0, N_NODES);
  k_agg1<<<6250, 256, 0, stream>>>(h1b, al1s, al1d, csr, row_start, deg,
                                   b1f, h1ob, gsum, gsq, 25000, N_NODES);

  // ---- layer 2 (BN finalize + BN/ELU + alpha2 fused into GEMM) ----
  k_gemm_mfma<64, true, false, false><<<(N_NODES + 63) / 64, 256, 0, stream>>>(
      h1ob, w2t, gsum, gsq, gamf, betf, a2sf, a2df, al2s, al2d,
      h2b, N_NODES, flags);
  k_agg2<<<(N_NODES + 3) / 4, 256, 0, stream>>>(h2b, al2s, al2d, csr, row_start, deg,
                                                b2f, d_out, flags, N_NODES);
}